// Round 13
// baseline (364.421 us; speedup 1.0000x reference)
//
#include <hip/hip_runtime.h>

#define IN_F 32
#define HID 64
#define OUTF 16
#define DPB 128                    // dsts per coarse bucket
#define CAPB 5120                  // coarse slots per bucket (E[b]=4096, +16 sigma)
#define RSL 80                     // rec slots per dst (Pois(32): P(m>80) ~ 1e-13)
#define EPB 4096                   // edges per front-end block
#define OVF_CAP 65536
#define ORD_NEG_INF 0x007FFFFFu    // ordenc(-inf), "empty" marker

typedef _Float16 v8h __attribute__((ext_vector_type(8)));
typedef float v4f __attribute__((ext_vector_type(4)));

__device__ __forceinline__ unsigned ordenc(float v) {
  unsigned b = __float_as_uint(v);
  return (b & 0x80000000u) ? ~b : (b | 0x80000000u);
}
__device__ __forceinline__ float orddec(unsigned u) {
  unsigned b = (u & 0x80000000u) ? (u & 0x7FFFFFFFu) : ~u;
  return __uint_as_float(b);
}
__device__ __forceinline__ unsigned short f2h_bits(float f) {
  _Float16 h = (_Float16)f; unsigned short u; __builtin_memcpy(&u, &h, 2); return u;
}
__device__ __forceinline__ float h_bits2f(unsigned short u) {
  _Float16 h; __builtin_memcpy(&h, &u, 2); return (float)h;
}

// ---------------------------------------------------------------------------
// P0: per-block coarse histogram (LDS atomics only; 4096 edges/block) +
// node_pre fused as extra blocks.
// ---------------------------------------------------------------------------
__global__ __launch_bounds__(256) void p0_kernel(
    const int* __restrict__ ei,
    const float* __restrict__ x, const float* __restrict__ W1,
    const float* __restrict__ b1,
    float* __restrict__ P, _Float16* __restrict__ Q,
    unsigned* __restrict__ hist, int E, int N, int nSB, int NBKT)
{
  if (blockIdx.x < (unsigned)nSB) {
    __shared__ unsigned h[512];                 // NBKT <= 512 (N <= 65536)
    for (int i = threadIdx.x; i < NBKT; i += 256) h[i] = 0;
    __syncthreads();
    const int base = blockIdx.x * EPB;
#pragma unroll 1
    for (int r = 0; r < 4; ++r) {
      const int b2 = base + r * 1024;
      int dd[4]; bool vv[4];
#pragma unroll
      for (int i = 0; i < 4; ++i) {
        int e = b2 + i * 256 + threadIdx.x;
        vv[i] = e < E;
        dd[i] = ei[(size_t)E + (vv[i] ? e : 0)];
      }
#pragma unroll
      for (int i = 0; i < 4; ++i)
        if (vv[i]) atomicAdd(&h[dd[i] >> 7], 1u);   // LDS atomic
    }
    __syncthreads();
    for (int i = threadIdx.x; i < NBKT; i += 256)
      hist[(size_t)blockIdx.x * NBKT + i] = h[i];
    return;
  }
  // ---------------- node_pre ----------------
  const int lane = threadIdx.x & 63;
  float w1d[IN_F], w1b[IN_F];
#pragma unroll
  for (int c = 0; c < IN_F; ++c) {
    w1b[c] = W1[(IN_F + c) * HID + lane];
    w1d[c] = W1[c * HID + lane] - w1b[c];
  }
  const float b1v = b1[lane];
  int gw = __builtin_amdgcn_readfirstlane((((int)blockIdx.x - nSB) << 2) | (threadIdx.x >> 6));
  const int nwaves = 512 << 2;
  for (int n = gw; n < N; n += nwaves) {
    float p = b1v, q = 0.f;
#pragma unroll
    for (int c = 0; c < IN_F; ++c) {
      float xv = x[n * IN_F + c];
      p = fmaf(xv, w1d[c], p);
      q = fmaf(xv, w1b[c], q);
    }
    P[n * HID + lane] = p;
    Q[n * HID + lane] = (_Float16)q;
  }
}

// ---------------------------------------------------------------------------
// scan: per-bucket column exclusive scan over blocks, in place (hist -> offsets),
// plus per-bucket totals. One block per bucket, 256 threads, Hillis-Steele.
// ---------------------------------------------------------------------------
__global__ __launch_bounds__(256) void scan_kernel(
    unsigned* __restrict__ hist, unsigned* __restrict__ totals,
    int nblk, int NBKT)
{
  __shared__ unsigned s[256];
  const int b = blockIdx.x;
  const int tid = threadIdx.x;
  unsigned running = 0;
  const int nch = (nblk + 255) >> 8;
  for (int c = 0; c < nch; ++c) {
    const int idx = c * 256 + tid;
    unsigned v = (idx < nblk) ? hist[(size_t)idx * NBKT + b] : 0u;
    s[tid] = v;
    __syncthreads();
#pragma unroll
    for (int off = 1; off < 256; off <<= 1) {
      unsigned t = (tid >= off) ? s[tid - off] : 0u;
      __syncthreads();
      s[tid] += t;
      __syncthreads();
    }
    const unsigned incl = s[tid];
    const unsigned tot = s[255];
    if (idx < nblk) hist[(size_t)idx * NBKT + b] = running + (incl - v);
    running += tot;
    __syncthreads();
  }
  if (tid == 0) totals[b] = running;
}

// ---------------------------------------------------------------------------
// P1: coarse scatter (4096 edges/block). Re-reads edges, LDS-ranks within
// (block, bucket), writes payload + dlo to the bucket's dense region.
// ---------------------------------------------------------------------------
__global__ __launch_bounds__(256) void p1_kernel(
    const int* __restrict__ ei, const float* __restrict__ ea,
    const unsigned* __restrict__ hist,
    uint2* __restrict__ cu, unsigned char* __restrict__ cdlo,
    uint4* __restrict__ ovf, int* __restrict__ ovf_cnt,
    int E, int NBKT)
{
  __shared__ unsigned h2[512];
  for (int i = threadIdx.x; i < NBKT; i += 256) h2[i] = 0;
  __syncthreads();
  const int base = blockIdx.x * EPB;
#pragma unroll 1
  for (int r = 0; r < 4; ++r) {
    const int b2 = base + r * 1024;
    int s[4], d[4]; bool v[4];
#pragma unroll
    for (int i = 0; i < 4; ++i) {
      int e = b2 + i * 256 + threadIdx.x;
      v[i] = e < E;
      int ec = v[i] ? e : 0;
      s[i] = ei[ec];
      d[i] = ei[(size_t)E + ec];
    }
    float a0[4], a1[4], a2[4];
#pragma unroll
    for (int i = 0; i < 4; ++i) {
      int ec = v[i] ? (b2 + i * 256 + threadIdx.x) : 0;
      a0[i] = ea[ec * 3 + 0]; a1[i] = ea[ec * 3 + 1]; a2[i] = ea[ec * 3 + 2];
    }
#pragma unroll
    for (int i = 0; i < 4; ++i) {
      if (!v[i]) continue;
      const int b = d[i] >> 7;
      const unsigned rr = atomicAdd(&h2[b], 1u);                   // LDS atomic
      const unsigned pos = hist[(size_t)blockIdx.x * NBKT + b] + rr;
      uint2 pay;
      pay.x = (unsigned)s[i] | ((unsigned)f2h_bits(a0[i]) << 16);  // src < 65536
      pay.y = (unsigned)f2h_bits(a1[i]) | ((unsigned)f2h_bits(a2[i]) << 16);
      if (pos < CAPB) {
        cu[(size_t)b * CAPB + pos] = pay;
        cdlo[(size_t)b * CAPB + pos] = (unsigned char)(d[i] & (DPB - 1));
      } else {
        int oi = atomicAdd(ovf_cnt, 1);
        if (oi < OVF_CAP) ovf[oi] = make_uint4(pay.x, pay.y, (unsigned)d[i], 0u);
      }
    }
  }
}

// ---------------------------------------------------------------------------
// P2: per-bucket final scatter. LDS per-dst rank (128 counters) -> linear
// rec[d*RSL + rank]; writes cnt[d]. All writes dense / L2-local.
// ---------------------------------------------------------------------------
__global__ __launch_bounds__(512) void p2_kernel(
    const uint2* __restrict__ cu, const unsigned char* __restrict__ cdlo,
    const unsigned* __restrict__ totals,
    uint2* __restrict__ rec, int* __restrict__ cnt,
    uint4* __restrict__ ovf, int* __restrict__ ovf_cnt, int N)
{
  __shared__ int c[DPB];
  const int b = blockIdx.x;
  const int tid = threadIdx.x;
  if (tid < DPB) c[tid] = 0;
  __syncthreads();
  const int nE = (int)min(totals[b], (unsigned)CAPB);
  for (int i = tid; i < nE; i += 512) {
    const uint2 pay = cu[(size_t)b * CAPB + i];
    const int dlo = cdlo[(size_t)b * CAPB + i];
    const int r = atomicAdd(&c[dlo], 1);                          // LDS atomic
    const int d = b * DPB + dlo;
    if (r < RSL) rec[(size_t)d * RSL + r] = pay;
    else {
      int oi = atomicAdd(ovf_cnt, 1);
      if (oi < OVF_CAP) ovf[oi] = make_uint4(pay.x, pay.y, (unsigned)d, 0u);
    }
  }
  __syncthreads();
  if (tid < DPB) {
    const int d = b * DPB + tid;
    if (d < N) cnt[d] = c[tid];
  }
}

// ---------------------------------------------------------------------------
// bucket (R13 = R12 with the launch-grid fix): octet-pipelined Q staging,
// partial-tile skip (phantom rows duplicate h[m-1] — bit-identical to padded
// records), 4 contiguous dsts per wave => 16 dsts per block => grid (N+15)/16.
// R12's failure was launching 49 blocks instead of 3125 (784/50000 dsts done).
// ---------------------------------------------------------------------------
__global__ __launch_bounds__(256) void bucket_kernel(
    const uint2* __restrict__ rec, const int* __restrict__ cnt,
    const float* __restrict__ W1, const float* __restrict__ W2,
    const float* __restrict__ P, const _Float16* __restrict__ Q,
    unsigned* __restrict__ agg, int N)
{
  __shared__ __align__(16) _Float16 hB[4][16][72];     // [wave][edge][ch]

  const int wave = threadIdx.x >> 6;
  const int lane = threadIdx.x & 63;
  const int quad = lane >> 4;
  const int eidx = lane & 15;
  // channel this lane stores in the final permuted row write
  const int mych = ((eidx >> 2) << 4) + (quad << 2) + (eidx & 3);

  // A-operand: W2^T fragments, fp16, loop-invariant (R2-verified).
  v8h a_frag[4][2];
#pragma unroll
  for (int t = 0; t < 4; ++t)
#pragma unroll
    for (int ks = 0; ks < 2; ++ks)
#pragma unroll
      for (int j = 0; j < 8; ++j)
        a_frag[t][ks][j] = (_Float16)W2[(ks * 32 + quad * 8 + j) * HID + t * 16 + eidx];

  const float w1c0 = W1[(2 * IN_F + 0) * HID + lane];
  const float w1c1 = W1[(2 * IN_F + 1) * HID + lane];
  const float w1c2 = W1[(2 * IN_F + 2) * HID + lane];

  const int gwave = __builtin_amdgcn_readfirstlane((blockIdx.x << 2) | wave);

  int d = gwave * 4;                 // 4 contiguous dsts per wave
  if (d >= N) return;
  const int dend = min(d + 4, N);

  int m; uint2 r0, r1; float pP;
  auto prefetch = [&](int dd) {
    m = min(cnt[dd], RSL);
    if (lane < m) r0 = rec[(size_t)dd * RSL + lane];
    if (m > 64) {       // wave-uniform rare branch (records 64..m)
      if (64 + lane < m) r1 = rec[(size_t)dd * RSL + 64 + lane];
    }
    pP = P[(size_t)dd * HID + lane];
  };

  prefetch(d);

  while (d < dend) {
    const int dn = d + 1;
    const int m_cur = m;
    const float pvl = pP;
    const uint2 ra = r0, rb = r1;   // active records for this dst

    if (m_cur > 0) {
      // ---- preload octets 0,1 (clamped to real edges; uniform guards) ----
      float qvA[8], qvB[8];
      {
        const int c0 = m_cur < 8 ? m_cur : 8;
        const int c1 = m_cur < 8 ? 0 : (m_cur < 16 ? m_cur - 8 : 8);
#pragma unroll
        for (int i = 0; i < 8; ++i)
          if (i < c0) {
            unsigned sx = (unsigned)__builtin_amdgcn_readlane((int)ra.x, i) & 0xFFFFu;
            qvA[i] = (float)Q[(size_t)sx * HID + lane];
          }
#pragma unroll
        for (int i = 0; i < 8; ++i)
          if (i < c1) {
            unsigned sx = (unsigned)__builtin_amdgcn_readlane((int)ra.x, 8 + i) & 0xFFFFu;
            qvB[i] = (float)Q[(size_t)sx * HID + lane];
          }
      }

      // ---- prefetch next dst (cnt -> records -> P), lands under tile work ----
      if (dn < dend) prefetch(dn);

      float maxv[4][4];
#pragma unroll
      for (int t = 0; t < 4; ++t)
#pragma unroll
        for (int r = 0; r < 4; ++r) maxv[t][r] = -INFINITY;

      const int ntile = (m_cur + 15) >> 4;
      for (int tb = 0; tb < ntile; ++tb) {
        const unsigned rsx = (tb < 4) ? ra.x : rb.x;
        const unsigned rsy = (tb < 4) ? ra.y : rb.y;
        const int b16 = (tb & 3) << 4;
        const int rem = m_cur - (tb << 4);           // real edges left (>=1)
        const int n0 = rem < 8 ? rem : 8;            // real rows in octet A
        const int n1 = rem < 8 ? 0 : (rem < 16 ? rem - 8 : 8);
        _Float16 hlast = (_Float16)0.f;

        // build real rows 0..n0-1 from qvA
#pragma unroll
        for (int i = 0; i < 8; ++i) {
          if (i < n0) {
            const unsigned rx = (unsigned)__builtin_amdgcn_readlane((int)rsx, b16 + i);
            const unsigned ry = (unsigned)__builtin_amdgcn_readlane((int)rsy, b16 + i);
            float pre = pvl + qvA[i];
            pre = fmaf(h_bits2f((unsigned short)(rx >> 16)), w1c0, pre);
            pre = fmaf(h_bits2f((unsigned short)(ry & 0xFFFFu)), w1c1, pre);
            pre = fmaf(h_bits2f((unsigned short)(ry >> 16)), w1c2, pre);
            _Float16 hv = (_Float16)fmaxf(pre, 0.f);
            hB[wave][i][lane] = hv;
            hlast = hv;
          }
        }
        // reissue qvA <- octet 2tb+2 (real slots only)
        {
          const int o = 2 * tb + 2;
          const int co = m_cur - (o << 3);
          if (co > 0) {
            const int cc = co < 8 ? co : 8;
            const unsigned rox = (o < 8) ? ra.x : rb.x;
            const int bo = (o & 7) << 3;
#pragma unroll
            for (int i = 0; i < 8; ++i)
              if (i < cc) {
                unsigned sx = (unsigned)__builtin_amdgcn_readlane((int)rox, bo + i) & 0xFFFFu;
                qvA[i] = (float)Q[(size_t)sx * HID + lane];
              }
          }
        }
        // build real rows 8..8+n1-1 from qvB
#pragma unroll
        for (int i = 0; i < 8; ++i) {
          if (i < n1) {
            const unsigned rx = (unsigned)__builtin_amdgcn_readlane((int)rsx, b16 + 8 + i);
            const unsigned ry = (unsigned)__builtin_amdgcn_readlane((int)rsy, b16 + 8 + i);
            float pre = pvl + qvB[i];
            pre = fmaf(h_bits2f((unsigned short)(rx >> 16)), w1c0, pre);
            pre = fmaf(h_bits2f((unsigned short)(ry & 0xFFFFu)), w1c1, pre);
            pre = fmaf(h_bits2f((unsigned short)(ry >> 16)), w1c2, pre);
            _Float16 hv = (_Float16)fmaxf(pre, 0.f);
            hB[wave][8 + i][lane] = hv;
            hlast = hv;
          }
        }
        // reissue qvB <- octet 2tb+3 (real slots only)
        {
          const int o = 2 * tb + 3;
          const int co = m_cur - (o << 3);
          if (co > 0) {
            const int cc = co < 8 ? co : 8;
            const unsigned rox = (o < 8) ? ra.x : rb.x;
            const int bo = (o & 7) << 3;
#pragma unroll
            for (int i = 0; i < 8; ++i)
              if (i < cc) {
                unsigned sx = (unsigned)__builtin_amdgcn_readlane((int)rox, bo + i) & 0xFFFFu;
                qvB[i] = (float)Q[(size_t)sx * HID + lane];
              }
          }
        }
        // phantom rows: duplicate last real edge's h (bit-identical to old padding)
        if (rem < 16) {
#pragma unroll
          for (int i = 0; i < 16; ++i)
            if (i >= rem) hB[wave][i][lane] = hlast;
        }
        __builtin_amdgcn_wave_barrier();

        const v8h bf0 = *(const v8h*)&hB[wave][eidx][quad * 8];
        const v8h bf1 = *(const v8h*)&hB[wave][eidx][32 + quad * 8];
#pragma unroll
        for (int t = 0; t < 4; ++t) {
          v4f acc = (v4f){0.f, 0.f, 0.f, 0.f};
          acc = __builtin_amdgcn_mfma_f32_16x16x32_f16(a_frag[t][0], bf0, acc, 0, 0, 0);
          acc = __builtin_amdgcn_mfma_f32_16x16x32_f16(a_frag[t][1], bf1, acc, 0, 0, 0);
#pragma unroll
          for (int r = 0; r < 4; ++r) maxv[t][r] = fmaxf(maxv[t][r], acc[r]);
        }
        __builtin_amdgcn_wave_barrier();
      }

      // ---- butterfly max over the 16 edge-columns, direct permuted row store ----
#pragma unroll
      for (int t = 0; t < 4; ++t)
#pragma unroll
        for (int r = 0; r < 4; ++r) {
          float v = maxv[t][r];
          v = fmaxf(v, __shfl_xor(v, 1, 64));
          v = fmaxf(v, __shfl_xor(v, 2, 64));
          v = fmaxf(v, __shfl_xor(v, 4, 64));
          v = fmaxf(v, __shfl_xor(v, 8, 64));
          maxv[t][r] = v;
        }
      float val = maxv[0][0];
#pragma unroll
      for (int t = 0; t < 4; ++t)
#pragma unroll
        for (int r = 0; r < 4; ++r)
          val = (eidx == t * 4 + r) ? maxv[t][r] : val;
      agg[(size_t)d * HID + mych] = ordenc(val);   // permutation within one 256B row
    } else {
      // empty dst; still run the next-dst prefetch to keep the pipeline primed
      if (dn < dend) prefetch(dn);
      agg[(size_t)d * HID + lane] = ORD_NEG_INF;
    }
    d = dn;
  }
}

// Fallback for overflow (expected ~0). Payload-form records {src|a0, a1|a2, d}.
// Same fp16-attr math as bucket, fp32 accumulation; atomicMax after bucket.
__global__ __launch_bounds__(256) void overflow_kernel(
    const uint4* __restrict__ ovf, const int* __restrict__ ovf_cnt,
    const float* __restrict__ W1, const float* __restrict__ W2,
    const float* __restrict__ P, const _Float16* __restrict__ Q,
    unsigned* __restrict__ agg)
{
  __shared__ float hsh[4][HID];
  const int wave = threadIdx.x >> 6;
  const int lane = threadIdx.x & 63;

  int M = *ovf_cnt;
  if (M > OVF_CAP) M = OVF_CAP;
  if (M == 0) return;

  float w2r[HID];
#pragma unroll
  for (int j = 0; j < HID; ++j) w2r[j] = W2[j * HID + lane];
  const float w1c0 = W1[(2 * IN_F + 0) * HID + lane];
  const float w1c1 = W1[(2 * IN_F + 1) * HID + lane];
  const float w1c2 = W1[(2 * IN_F + 2) * HID + lane];

  const int gwave = __builtin_amdgcn_readfirstlane((blockIdx.x << 2) | wave);
  const int nw = gridDim.x << 2;
  for (int k = gwave; k < M; k += nw) {
    const uint4 o = ovf[k];
    const int s = (int)(o.x & 0xFFFFu);
    const int d = (int)o.z;
    float pre = P[(size_t)d * HID + lane] + (float)Q[(size_t)s * HID + lane];
    pre = fmaf(h_bits2f((unsigned short)(o.x >> 16)), w1c0, pre);
    pre = fmaf(h_bits2f((unsigned short)(o.y & 0xFFFFu)), w1c1, pre);
    pre = fmaf(h_bits2f((unsigned short)(o.y >> 16)), w1c2, pre);
    hsh[wave][lane] = fmaxf(pre, 0.f);
    __builtin_amdgcn_wave_barrier();
    float mv = 0.f;
#pragma unroll
    for (int j = 0; j < HID; ++j) mv = fmaf(hsh[wave][j], w2r[j], mv);
    atomicMax(&agg[(size_t)d * HID + lane], ordenc(mv));
    __builtin_amdgcn_wave_barrier();
  }
}

// 16 nodes per block: decode agg (empty -> 0, else +b2), out = sigmoid(agg @ Wo + bo)
__global__ __launch_bounds__(256) void out_kernel(
    const unsigned* __restrict__ agg,
    const float* __restrict__ b2,
    const float* __restrict__ Wo, const float* __restrict__ bo,
    float* __restrict__ out, int N)
{
  __shared__ float Wos[HID * OUTF];
  __shared__ float bos[OUTF];
  __shared__ float b2s[HID];
  __shared__ float aggs[16][HID + 1];

  for (int i = threadIdx.x; i < HID * OUTF; i += 256) Wos[i] = Wo[i];
  if (threadIdx.x < OUTF) bos[threadIdx.x] = bo[threadIdx.x];
  if (threadIdx.x < HID) b2s[threadIdx.x] = b2[threadIdx.x];
  __syncthreads();

  const int nodeBase = blockIdx.x * 16;
  {
    int ln = threadIdx.x >> 4;
    int k0 = (threadIdx.x & 15) * 4;
    int n = nodeBase + ln;
    if (n < N) {
      const uint4 u = *(const uint4*)&agg[(size_t)n * HID + k0];
      aggs[ln][k0 + 0] = (u.x == ORD_NEG_INF) ? 0.f : orddec(u.x) + b2s[k0 + 0];
      aggs[ln][k0 + 1] = (u.y == ORD_NEG_INF) ? 0.f : orddec(u.y) + b2s[k0 + 1];
      aggs[ln][k0 + 2] = (u.z == ORD_NEG_INF) ? 0.f : orddec(u.z) + b2s[k0 + 2];
      aggs[ln][k0 + 3] = (u.w == ORD_NEG_INF) ? 0.f : orddec(u.w) + b2s[k0 + 3];
    }
  }
  __syncthreads();
  {
    int ln = threadIdx.x >> 4;
    int o = threadIdx.x & 15;
    int n = nodeBase + ln;
    if (n < N) {
      float acc = bos[o];
#pragma unroll
      for (int k = 0; k < HID; ++k) acc = fmaf(aggs[ln][k], Wos[k * OUTF + o], acc);
      out[n * OUTF + o] = 1.f / (1.f + __expf(-acc));
    }
  }
}

extern "C" void kernel_launch(void* const* d_in, const int* in_sizes, int n_in,
                              void* d_out, int out_size, void* d_ws, size_t ws_size,
                              hipStream_t stream) {
  const float* x  = (const float*)d_in[0];
  const int*   ei = (const int*)d_in[1];
  const float* ea = (const float*)d_in[2];
  const float* W1 = (const float*)d_in[3];
  const float* b1 = (const float*)d_in[4];
  const float* W2 = (const float*)d_in[5];
  const float* b2 = (const float*)d_in[6];
  const float* Wo = (const float*)d_in[7];
  const float* bo = (const float*)d_in[8];
  float* out = (float*)d_out;

  const int N = in_sizes[0] / IN_F;    // 50000
  const int E = in_sizes[1] / 2;       // 1600000
  const int NBKT = (N + DPB - 1) / DPB;   // 391
  const int nSB  = (E + EPB - 1) / EPB;   // 391 (4096 edges/block)

  // ws layout (16B-aligned regions), ~84 MB total:
  // P(12.8M) | Q fp16(6.4M) | agg(12.8M) | rec N*RSL*8(32M) | cu NBKT*CAPB*8(16M)
  // | hist nSB*NBKT*4(0.61M) | totals | cnt(0.2M) | cdlo NBKT*CAPB(2M) | ovf_cnt | ovf(1M)
  char* w = (char*)d_ws;
  auto align16 = [](size_t v) { return (v + 15) & ~(size_t)15; };
  float*     Pp   = (float*)w;       w += align16((size_t)N * HID * 4);
  _Float16*  Qp   = (_Float16*)w;    w += align16((size_t)N * HID * 2);
  unsigned*  agg  = (unsigned*)w;    w += align16((size_t)N * HID * 4);
  uint2*     rec  = (uint2*)w;       w += align16((size_t)N * RSL * 8);
  uint2*     cu   = (uint2*)w;       w += align16((size_t)NBKT * CAPB * 8);
  unsigned*  hist = (unsigned*)w;    w += align16((size_t)nSB * NBKT * 4);
  unsigned*  tot  = (unsigned*)w;    w += align16((size_t)NBKT * 4);
  int*       cnt  = (int*)w;         w += align16((size_t)N * 4);
  unsigned char* cdlo = (unsigned char*)w; w += align16((size_t)NBKT * CAPB);
  int*   ovf_cnt  = (int*)w;         w += 16;
  uint4*     ovf  = (uint4*)w;

  hipMemsetAsync(ovf_cnt, 0, 16, stream);

  p0_kernel<<<nSB + 512, 256, 0, stream>>>(ei, x, W1, b1, Pp, Qp, hist, E, N, nSB, NBKT);
  scan_kernel<<<NBKT, 256, 0, stream>>>(hist, tot, nSB, NBKT);
  p1_kernel<<<nSB, 256, 0, stream>>>(ei, ea, hist, cu, cdlo, ovf, ovf_cnt, E, NBKT);
  p2_kernel<<<NBKT, 512, 0, stream>>>(cu, cdlo, tot, rec, cnt, ovf, ovf_cnt, N);
  bucket_kernel<<<(N + 15) / 16, 256, 0, stream>>>(rec, cnt, W1, W2, Pp, Qp, agg, N);
  overflow_kernel<<<256, 256, 0, stream>>>(ovf, ovf_cnt, W1, W2, Pp, Qp, agg);
  out_kernel<<<(N + 15) / 16, 256, 0, stream>>>(agg, b2, Wo, bo, out, N);
}

// Round 14
// 258.310 us; speedup vs baseline: 1.4108x; 1.4108x over previous
//
#include <hip/hip_runtime.h>

#define IN_F 32
#define HID 64
#define OUTF 16
#define DPB 128                    // dsts per coarse bucket
#define CAPB 5120                  // coarse slots per bucket (E[b]=4096, +16 sigma)
#define RSL 80                     // rec slots per dst (Pois(32): P(m>80) ~ 1e-13)
#define EPB 4096                   // edges per front-end block
#define OVF_CAP 65536
#define ORD_NEG_INF 0x007FFFFFu    // ordenc(-inf), "empty" marker

typedef _Float16 v8h __attribute__((ext_vector_type(8)));
typedef float v4f __attribute__((ext_vector_type(4)));

__device__ __forceinline__ unsigned ordenc(float v) {
  unsigned b = __float_as_uint(v);
  return (b & 0x80000000u) ? ~b : (b | 0x80000000u);
}
__device__ __forceinline__ float orddec(unsigned u) {
  unsigned b = (u & 0x80000000u) ? (u & 0x7FFFFFFFu) : ~u;
  return __uint_as_float(b);
}
__device__ __forceinline__ unsigned short f2h_bits(float f) {
  _Float16 h = (_Float16)f; unsigned short u; __builtin_memcpy(&u, &h, 2); return u;
}
__device__ __forceinline__ float h_bits2f(unsigned short u) {
  _Float16 h; __builtin_memcpy(&h, &u, 2); return (float)h;
}

// ---------------------------------------------------------------------------
// P0: per-block coarse histogram (LDS atomics only; 4096 edges/block) +
// node_pre fused as extra blocks.
// ---------------------------------------------------------------------------
__global__ __launch_bounds__(256) void p0_kernel(
    const int* __restrict__ ei,
    const float* __restrict__ x, const float* __restrict__ W1,
    const float* __restrict__ b1,
    float* __restrict__ P, _Float16* __restrict__ Q,
    unsigned* __restrict__ hist, int E, int N, int nSB, int NBKT)
{
  if (blockIdx.x < (unsigned)nSB) {
    __shared__ unsigned h[512];                 // NBKT <= 512 (N <= 65536)
    for (int i = threadIdx.x; i < NBKT; i += 256) h[i] = 0;
    __syncthreads();
    const int base = blockIdx.x * EPB;
#pragma unroll 1
    for (int r = 0; r < 4; ++r) {
      const int b2 = base + r * 1024;
      int dd[4]; bool vv[4];
#pragma unroll
      for (int i = 0; i < 4; ++i) {
        int e = b2 + i * 256 + threadIdx.x;
        vv[i] = e < E;
        dd[i] = ei[(size_t)E + (vv[i] ? e : 0)];
      }
#pragma unroll
      for (int i = 0; i < 4; ++i)
        if (vv[i]) atomicAdd(&h[dd[i] >> 7], 1u);   // LDS atomic
    }
    __syncthreads();
    for (int i = threadIdx.x; i < NBKT; i += 256)
      hist[(size_t)blockIdx.x * NBKT + i] = h[i];
    return;
  }
  // ---------------- node_pre ----------------
  const int lane = threadIdx.x & 63;
  float w1d[IN_F], w1b[IN_F];
#pragma unroll
  for (int c = 0; c < IN_F; ++c) {
    w1b[c] = W1[(IN_F + c) * HID + lane];
    w1d[c] = W1[c * HID + lane] - w1b[c];
  }
  const float b1v = b1[lane];
  int gw = __builtin_amdgcn_readfirstlane((((int)blockIdx.x - nSB) << 2) | (threadIdx.x >> 6));
  const int nwaves = 512 << 2;
  for (int n = gw; n < N; n += nwaves) {
    float p = b1v, q = 0.f;
#pragma unroll
    for (int c = 0; c < IN_F; ++c) {
      float xv = x[n * IN_F + c];
      p = fmaf(xv, w1d[c], p);
      q = fmaf(xv, w1b[c], q);
    }
    P[n * HID + lane] = p;
    Q[n * HID + lane] = (_Float16)q;
  }
}

// ---------------------------------------------------------------------------
// scan: per-bucket column exclusive scan over blocks, in place (hist -> offsets),
// plus per-bucket totals. One block per bucket, 256 threads, Hillis-Steele.
// ---------------------------------------------------------------------------
__global__ __launch_bounds__(256) void scan_kernel(
    unsigned* __restrict__ hist, unsigned* __restrict__ totals,
    int nblk, int NBKT)
{
  __shared__ unsigned s[256];
  const int b = blockIdx.x;
  const int tid = threadIdx.x;
  unsigned running = 0;
  const int nch = (nblk + 255) >> 8;
  for (int c = 0; c < nch; ++c) {
    const int idx = c * 256 + tid;
    unsigned v = (idx < nblk) ? hist[(size_t)idx * NBKT + b] : 0u;
    s[tid] = v;
    __syncthreads();
#pragma unroll
    for (int off = 1; off < 256; off <<= 1) {
      unsigned t = (tid >= off) ? s[tid - off] : 0u;
      __syncthreads();
      s[tid] += t;
      __syncthreads();
    }
    const unsigned incl = s[tid];
    const unsigned tot = s[255];
    if (idx < nblk) hist[(size_t)idx * NBKT + b] = running + (incl - v);
    running += tot;
    __syncthreads();
  }
  if (tid == 0) totals[b] = running;
}

// ---------------------------------------------------------------------------
// P1: coarse scatter (4096 edges/block). Re-reads edges, LDS-ranks within
// (block, bucket), writes payload + dlo to the bucket's dense region.
// ---------------------------------------------------------------------------
__global__ __launch_bounds__(256) void p1_kernel(
    const int* __restrict__ ei, const float* __restrict__ ea,
    const unsigned* __restrict__ hist,
    uint2* __restrict__ cu, unsigned char* __restrict__ cdlo,
    uint4* __restrict__ ovf, int* __restrict__ ovf_cnt,
    int E, int NBKT)
{
  __shared__ unsigned h2[512];
  for (int i = threadIdx.x; i < NBKT; i += 256) h2[i] = 0;
  __syncthreads();
  const int base = blockIdx.x * EPB;
#pragma unroll 1
  for (int r = 0; r < 4; ++r) {
    const int b2 = base + r * 1024;
    int s[4], d[4]; bool v[4];
#pragma unroll
    for (int i = 0; i < 4; ++i) {
      int e = b2 + i * 256 + threadIdx.x;
      v[i] = e < E;
      int ec = v[i] ? e : 0;
      s[i] = ei[ec];
      d[i] = ei[(size_t)E + ec];
    }
    float a0[4], a1[4], a2[4];
#pragma unroll
    for (int i = 0; i < 4; ++i) {
      int ec = v[i] ? (b2 + i * 256 + threadIdx.x) : 0;
      a0[i] = ea[ec * 3 + 0]; a1[i] = ea[ec * 3 + 1]; a2[i] = ea[ec * 3 + 2];
    }
#pragma unroll
    for (int i = 0; i < 4; ++i) {
      if (!v[i]) continue;
      const int b = d[i] >> 7;
      const unsigned rr = atomicAdd(&h2[b], 1u);                   // LDS atomic
      const unsigned pos = hist[(size_t)blockIdx.x * NBKT + b] + rr;
      uint2 pay;
      pay.x = (unsigned)s[i] | ((unsigned)f2h_bits(a0[i]) << 16);  // src < 65536
      pay.y = (unsigned)f2h_bits(a1[i]) | ((unsigned)f2h_bits(a2[i]) << 16);
      if (pos < CAPB) {
        cu[(size_t)b * CAPB + pos] = pay;
        cdlo[(size_t)b * CAPB + pos] = (unsigned char)(d[i] & (DPB - 1));
      } else {
        int oi = atomicAdd(ovf_cnt, 1);
        if (oi < OVF_CAP) ovf[oi] = make_uint4(pay.x, pay.y, (unsigned)d[i], 0u);
      }
    }
  }
}

// ---------------------------------------------------------------------------
// P2: per-bucket final scatter. LDS per-dst rank (128 counters) -> linear
// rec[d*RSL + rank]; writes cnt[d]. All writes dense / L2-local.
// ---------------------------------------------------------------------------
__global__ __launch_bounds__(512) void p2_kernel(
    const uint2* __restrict__ cu, const unsigned char* __restrict__ cdlo,
    const unsigned* __restrict__ totals,
    uint2* __restrict__ rec, int* __restrict__ cnt,
    uint4* __restrict__ ovf, int* __restrict__ ovf_cnt, int N)
{
  __shared__ int c[DPB];
  const int b = blockIdx.x;
  const int tid = threadIdx.x;
  if (tid < DPB) c[tid] = 0;
  __syncthreads();
  const int nE = (int)min(totals[b], (unsigned)CAPB);
  for (int i = tid; i < nE; i += 512) {
    const uint2 pay = cu[(size_t)b * CAPB + i];
    const int dlo = cdlo[(size_t)b * CAPB + i];
    const int r = atomicAdd(&c[dlo], 1);                          // LDS atomic
    const int d = b * DPB + dlo;
    if (r < RSL) rec[(size_t)d * RSL + r] = pay;
    else {
      int oi = atomicAdd(ovf_cnt, 1);
      if (oi < OVF_CAP) ovf[oi] = make_uint4(pay.x, pay.y, (unsigned)d, 0u);
    }
  }
  __syncthreads();
  if (tid < DPB) {
    const int d = b * DPB + tid;
    if (d < N) cnt[d] = c[tid];
  }
}

// ---------------------------------------------------------------------------
// bucket: R11 version VERBATIM (measured 104.7 us — best). R13 post-mortem:
// guarded (branch-fenced) Q loads doubled stall at identical VALU work; in
// latency-critical inner loops, straight-line redundant work beats guarded
// minimal work. Octet-pipelined Q double-buffer (qvA/qvB, 8 regs each),
// strided dst assignment, padded records, VGPR ~60.
// ---------------------------------------------------------------------------
__global__ __launch_bounds__(256) void bucket_kernel(
    const uint2* __restrict__ rec, const int* __restrict__ cnt,
    const float* __restrict__ W1, const float* __restrict__ W2,
    const float* __restrict__ P, const _Float16* __restrict__ Q,
    unsigned* __restrict__ agg, int N)
{
  __shared__ __align__(16) _Float16 hB[4][16][72];     // [wave][edge][ch]

  const int wave = threadIdx.x >> 6;
  const int lane = threadIdx.x & 63;
  const int quad = lane >> 4;
  const int eidx = lane & 15;
  // channel this lane stores in the final permuted row write
  const int mych = ((eidx >> 2) << 4) + (quad << 2) + (eidx & 3);

  // A-operand: W2^T fragments, fp16, loop-invariant (R2-verified).
  v8h a_frag[4][2];
#pragma unroll
  for (int t = 0; t < 4; ++t)
#pragma unroll
    for (int ks = 0; ks < 2; ++ks)
#pragma unroll
      for (int j = 0; j < 8; ++j)
        a_frag[t][ks][j] = (_Float16)W2[(ks * 32 + quad * 8 + j) * HID + t * 16 + eidx];

  const float w1c0 = W1[(2 * IN_F + 0) * HID + lane];
  const float w1c1 = W1[(2 * IN_F + 1) * HID + lane];
  const float w1c2 = W1[(2 * IN_F + 2) * HID + lane];

  const int gwave = __builtin_amdgcn_readfirstlane((blockIdx.x << 2) | wave);
  const int nw = gridDim.x << 2;

  int d = gwave;
  if (d >= N) return;   // waves are independent (no cross-wave LDS / syncthreads)

  int m; uint2 r0, r1; float pP;
  auto prefetch = [&](int dd) {
    m = min(cnt[dd], RSL);
    if (lane < m) r0 = rec[(size_t)dd * RSL + lane];
    if (m > 64) {       // wave-uniform rare branch (records 64..m)
      if (64 + lane < m) r1 = rec[(size_t)dd * RSL + 64 + lane];
    }
    pP = P[(size_t)dd * HID + lane];
  };

  prefetch(d);

  while (d < N) {
    const int dn = d + nw;
    const int m_cur = m;
    const float pvl = pP;
    uint2 ra = r0, rb = r1;   // active records for this dst

    if (m_cur > 0) {
      // ---- pad reg records: lanes >= m_cur get a copy of the last record ----
      {
        const int lm = m_cur - 1;
        unsigned rlx, rly;
        if (lm < 64) {
          rlx = (unsigned)__builtin_amdgcn_readlane((int)ra.x, lm);
          rly = (unsigned)__builtin_amdgcn_readlane((int)ra.y, lm);
        } else {
          rlx = (unsigned)__builtin_amdgcn_readlane((int)rb.x, lm & 63);
          rly = (unsigned)__builtin_amdgcn_readlane((int)rb.y, lm & 63);
        }
        if (lane >= m_cur)      { ra.x = rlx; ra.y = rly; }
        if (lane + 64 >= m_cur) { rb.x = rlx; rb.y = rly; }
      }

      // ---- preload octets 0,1 (uniform src -> saddr loads) ----
      float qvA[8], qvB[8];
#pragma unroll
      for (int i = 0; i < 8; ++i) {
        unsigned sx = (unsigned)__builtin_amdgcn_readlane((int)ra.x, i) & 0xFFFFu;
        qvA[i] = (float)Q[(size_t)sx * HID + lane];
      }
#pragma unroll
      for (int i = 0; i < 8; ++i) {
        unsigned sx = (unsigned)__builtin_amdgcn_readlane((int)ra.x, 8 + i) & 0xFFFFu;
        qvB[i] = (float)Q[(size_t)sx * HID + lane];
      }

      // ---- prefetch next dst (cnt -> records -> P), lands under tile work ----
      if (dn < N) prefetch(dn);

      // ---- process current dst: 16-edge MFMA tiles (ntile <= 5) ----
      float maxv[4][4];
#pragma unroll
      for (int t = 0; t < 4; ++t)
#pragma unroll
        for (int r = 0; r < 4; ++r) maxv[t][r] = -INFINITY;

      const int ntile = (m_cur + 15) >> 4;
      const int noct = ntile << 1;
      for (int tb = 0; tb < ntile; ++tb) {
        const unsigned rsx = (tb < 4) ? ra.x : rb.x;
        const unsigned rsy = (tb < 4) ? ra.y : rb.y;
        const int b16 = (tb & 3) << 4;

        // build rows 0-7 from qvA (octet 2tb)
#pragma unroll
        for (int i = 0; i < 8; ++i) {
          const unsigned rx = (unsigned)__builtin_amdgcn_readlane((int)rsx, b16 + i);
          const unsigned ry = (unsigned)__builtin_amdgcn_readlane((int)rsy, b16 + i);
          float pre = pvl + qvA[i];
          pre = fmaf(h_bits2f((unsigned short)(rx >> 16)), w1c0, pre);
          pre = fmaf(h_bits2f((unsigned short)(ry & 0xFFFFu)), w1c1, pre);
          pre = fmaf(h_bits2f((unsigned short)(ry >> 16)), w1c2, pre);
          hB[wave][i][lane] = (_Float16)fmaxf(pre, 0.f);
        }
        // reissue qvA <- octet 2tb+2 (covered by rows 8-15 build + MFMA + next rows 0-7)
        {
          const int o = 2 * tb + 2;
          if (o < noct) {
            const unsigned rox = (o < 8) ? ra.x : rb.x;
            const int bo = (o & 7) << 3;
#pragma unroll
            for (int i = 0; i < 8; ++i) {
              unsigned sx = (unsigned)__builtin_amdgcn_readlane((int)rox, bo + i) & 0xFFFFu;
              qvA[i] = (float)Q[(size_t)sx * HID + lane];
            }
          }
        }
        // build rows 8-15 from qvB (octet 2tb+1)
#pragma unroll
        for (int i = 0; i < 8; ++i) {
          const unsigned rx = (unsigned)__builtin_amdgcn_readlane((int)rsx, b16 + 8 + i);
          const unsigned ry = (unsigned)__builtin_amdgcn_readlane((int)rsy, b16 + 8 + i);
          float pre = pvl + qvB[i];
          pre = fmaf(h_bits2f((unsigned short)(rx >> 16)), w1c0, pre);
          pre = fmaf(h_bits2f((unsigned short)(ry & 0xFFFFu)), w1c1, pre);
          pre = fmaf(h_bits2f((unsigned short)(ry >> 16)), w1c2, pre);
          hB[wave][8 + i][lane] = (_Float16)fmaxf(pre, 0.f);
        }
        // reissue qvB <- octet 2tb+3
        {
          const int o = 2 * tb + 3;
          if (o < noct) {
            const unsigned rox = (o < 8) ? ra.x : rb.x;
            const int bo = (o & 7) << 3;
#pragma unroll
            for (int i = 0; i < 8; ++i) {
              unsigned sx = (unsigned)__builtin_amdgcn_readlane((int)rox, bo + i) & 0xFFFFu;
              qvB[i] = (float)Q[(size_t)sx * HID + lane];
            }
          }
        }
        __builtin_amdgcn_wave_barrier();

        const v8h bf0 = *(const v8h*)&hB[wave][eidx][quad * 8];
        const v8h bf1 = *(const v8h*)&hB[wave][eidx][32 + quad * 8];
#pragma unroll
        for (int t = 0; t < 4; ++t) {
          v4f acc = (v4f){0.f, 0.f, 0.f, 0.f};
          acc = __builtin_amdgcn_mfma_f32_16x16x32_f16(a_frag[t][0], bf0, acc, 0, 0, 0);
          acc = __builtin_amdgcn_mfma_f32_16x16x32_f16(a_frag[t][1], bf1, acc, 0, 0, 0);
#pragma unroll
          for (int r = 0; r < 4; ++r) maxv[t][r] = fmaxf(maxv[t][r], acc[r]);
        }
        __builtin_amdgcn_wave_barrier();
      }

      // ---- butterfly max over the 16 edge-columns, direct permuted row store ----
#pragma unroll
      for (int t = 0; t < 4; ++t)
#pragma unroll
        for (int r = 0; r < 4; ++r) {
          float v = maxv[t][r];
          v = fmaxf(v, __shfl_xor(v, 1, 64));
          v = fmaxf(v, __shfl_xor(v, 2, 64));
          v = fmaxf(v, __shfl_xor(v, 4, 64));
          v = fmaxf(v, __shfl_xor(v, 8, 64));
          maxv[t][r] = v;
        }
      float val = maxv[0][0];
#pragma unroll
      for (int t = 0; t < 4; ++t)
#pragma unroll
        for (int r = 0; r < 4; ++r)
          val = (eidx == t * 4 + r) ? maxv[t][r] : val;
      agg[(size_t)d * HID + mych] = ordenc(val);   // permutation within one 256B row
    } else {
      // empty dst; still run the next-dst prefetch to keep the pipeline primed
      if (dn < N) prefetch(dn);
      agg[(size_t)d * HID + lane] = ORD_NEG_INF;
    }
    d = dn;
  }
}

// Fallback for overflow (expected ~0). Payload-form records {src|a0, a1|a2, d}.
// Same fp16-attr math as bucket, fp32 accumulation; atomicMax after bucket.
__global__ __launch_bounds__(256) void overflow_kernel(
    const uint4* __restrict__ ovf, const int* __restrict__ ovf_cnt,
    const float* __restrict__ W1, const float* __restrict__ W2,
    const float* __restrict__ P, const _Float16* __restrict__ Q,
    unsigned* __restrict__ agg)
{
  __shared__ float hsh[4][HID];
  const int wave = threadIdx.x >> 6;
  const int lane = threadIdx.x & 63;

  int M = *ovf_cnt;
  if (M > OVF_CAP) M = OVF_CAP;
  if (M == 0) return;

  float w2r[HID];
#pragma unroll
  for (int j = 0; j < HID; ++j) w2r[j] = W2[j * HID + lane];
  const float w1c0 = W1[(2 * IN_F + 0) * HID + lane];
  const float w1c1 = W1[(2 * IN_F + 1) * HID + lane];
  const float w1c2 = W1[(2 * IN_F + 2) * HID + lane];

  const int gwave = __builtin_amdgcn_readfirstlane((blockIdx.x << 2) | wave);
  const int nw = gridDim.x << 2;
  for (int k = gwave; k < M; k += nw) {
    const uint4 o = ovf[k];
    const int s = (int)(o.x & 0xFFFFu);
    const int d = (int)o.z;
    float pre = P[(size_t)d * HID + lane] + (float)Q[(size_t)s * HID + lane];
    pre = fmaf(h_bits2f((unsigned short)(o.x >> 16)), w1c0, pre);
    pre = fmaf(h_bits2f((unsigned short)(o.y & 0xFFFFu)), w1c1, pre);
    pre = fmaf(h_bits2f((unsigned short)(o.y >> 16)), w1c2, pre);
    hsh[wave][lane] = fmaxf(pre, 0.f);
    __builtin_amdgcn_wave_barrier();
    float mv = 0.f;
#pragma unroll
    for (int j = 0; j < HID; ++j) mv = fmaf(hsh[wave][j], w2r[j], mv);
    atomicMax(&agg[(size_t)d * HID + lane], ordenc(mv));
    __builtin_amdgcn_wave_barrier();
  }
}

// 16 nodes per block: decode agg (empty -> 0, else +b2), out = sigmoid(agg @ Wo + bo)
__global__ __launch_bounds__(256) void out_kernel(
    const unsigned* __restrict__ agg,
    const float* __restrict__ b2,
    const float* __restrict__ Wo, const float* __restrict__ bo,
    float* __restrict__ out, int N)
{
  __shared__ float Wos[HID * OUTF];
  __shared__ float bos[OUTF];
  __shared__ float b2s[HID];
  __shared__ float aggs[16][HID + 1];

  for (int i = threadIdx.x; i < HID * OUTF; i += 256) Wos[i] = Wo[i];
  if (threadIdx.x < OUTF) bos[threadIdx.x] = bo[threadIdx.x];
  if (threadIdx.x < HID) b2s[threadIdx.x] = b2[threadIdx.x];
  __syncthreads();

  const int nodeBase = blockIdx.x * 16;
  {
    int ln = threadIdx.x >> 4;
    int k0 = (threadIdx.x & 15) * 4;
    int n = nodeBase + ln;
    if (n < N) {
      const uint4 u = *(const uint4*)&agg[(size_t)n * HID + k0];
      aggs[ln][k0 + 0] = (u.x == ORD_NEG_INF) ? 0.f : orddec(u.x) + b2s[k0 + 0];
      aggs[ln][k0 + 1] = (u.y == ORD_NEG_INF) ? 0.f : orddec(u.y) + b2s[k0 + 1];
      aggs[ln][k0 + 2] = (u.z == ORD_NEG_INF) ? 0.f : orddec(u.z) + b2s[k0 + 2];
      aggs[ln][k0 + 3] = (u.w == ORD_NEG_INF) ? 0.f : orddec(u.w) + b2s[k0 + 3];
    }
  }
  __syncthreads();
  {
    int ln = threadIdx.x >> 4;
    int o = threadIdx.x & 15;
    int n = nodeBase + ln;
    if (n < N) {
      float acc = bos[o];
#pragma unroll
      for (int k = 0; k < HID; ++k) acc = fmaf(aggs[ln][k], Wos[k * OUTF + o], acc);
      out[n * OUTF + o] = 1.f / (1.f + __expf(-acc));
    }
  }
}

extern "C" void kernel_launch(void* const* d_in, const int* in_sizes, int n_in,
                              void* d_out, int out_size, void* d_ws, size_t ws_size,
                              hipStream_t stream) {
  const float* x  = (const float*)d_in[0];
  const int*   ei = (const int*)d_in[1];
  const float* ea = (const float*)d_in[2];
  const float* W1 = (const float*)d_in[3];
  const float* b1 = (const float*)d_in[4];
  const float* W2 = (const float*)d_in[5];
  const float* b2 = (const float*)d_in[6];
  const float* Wo = (const float*)d_in[7];
  const float* bo = (const float*)d_in[8];
  float* out = (float*)d_out;

  const int N = in_sizes[0] / IN_F;    // 50000
  const int E = in_sizes[1] / 2;       // 1600000
  const int NBKT = (N + DPB - 1) / DPB;   // 391
  const int nSB  = (E + EPB - 1) / EPB;   // 391 (4096 edges/block)

  // ws layout (16B-aligned regions), ~84 MB total:
  // P(12.8M) | Q fp16(6.4M) | agg(12.8M) | rec N*RSL*8(32M) | cu NBKT*CAPB*8(16M)
  // | hist nSB*NBKT*4(0.61M) | totals | cnt(0.2M) | cdlo NBKT*CAPB(2M) | ovf_cnt | ovf(1M)
  char* w = (char*)d_ws;
  auto align16 = [](size_t v) { return (v + 15) & ~(size_t)15; };
  float*     Pp   = (float*)w;       w += align16((size_t)N * HID * 4);
  _Float16*  Qp   = (_Float16*)w;    w += align16((size_t)N * HID * 2);
  unsigned*  agg  = (unsigned*)w;    w += align16((size_t)N * HID * 4);
  uint2*     rec  = (uint2*)w;       w += align16((size_t)N * RSL * 8);
  uint2*     cu   = (uint2*)w;       w += align16((size_t)NBKT * CAPB * 8);
  unsigned*  hist = (unsigned*)w;    w += align16((size_t)nSB * NBKT * 4);
  unsigned*  tot  = (unsigned*)w;    w += align16((size_t)NBKT * 4);
  int*       cnt  = (int*)w;         w += align16((size_t)N * 4);
  unsigned char* cdlo = (unsigned char*)w; w += align16((size_t)NBKT * CAPB);
  int*   ovf_cnt  = (int*)w;         w += 16;
  uint4*     ovf  = (uint4*)w;

  hipMemsetAsync(ovf_cnt, 0, 16, stream);

  p0_kernel<<<nSB + 512, 256, 0, stream>>>(ei, x, W1, b1, Pp, Qp, hist, E, N, nSB, NBKT);
  scan_kernel<<<NBKT, 256, 0, stream>>>(hist, tot, nSB, NBKT);
  p1_kernel<<<nSB, 256, 0, stream>>>(ei, ea, hist, cu, cdlo, ovf, ovf_cnt, E, NBKT);
  p2_kernel<<<NBKT, 512, 0, stream>>>(cu, cdlo, tot, rec, cnt, ovf, ovf_cnt, N);
  bucket_kernel<<<4096, 256, 0, stream>>>(rec, cnt, W1, W2, Pp, Qp, agg, N);
  overflow_kernel<<<256, 256, 0, stream>>>(ovf, ovf_cnt, W1, W2, Pp, Qp, agg);
  out_kernel<<<(N + 15) / 16, 256, 0, stream>>>(agg, b2, Wo, bo, out, N);
}

// Round 15
// 253.364 us; speedup vs baseline: 1.4383x; 1.0195x over previous
//
#include <hip/hip_runtime.h>

#define IN_F 32
#define HID 64
#define OUTF 16
#define DPB 128                    // dsts per coarse bucket
#define CAPB 5120                  // coarse slots per bucket (E[b]=4096, +16 sigma)
#define RSL 80                     // rec slots per dst (Pois(32): P(m>80) ~ 1e-13)
#define EPB 4096                   // edges per front-end block
#define OVF_CAP 65536
#define ORD_NEG_INF 0x007FFFFFu    // ordenc(-inf), "empty" marker

typedef _Float16 v8h __attribute__((ext_vector_type(8)));
typedef float v4f __attribute__((ext_vector_type(4)));

__device__ __forceinline__ unsigned ordenc(float v) {
  unsigned b = __float_as_uint(v);
  return (b & 0x80000000u) ? ~b : (b | 0x80000000u);
}
__device__ __forceinline__ float orddec(unsigned u) {
  unsigned b = (u & 0x80000000u) ? (u & 0x7FFFFFFFu) : ~u;
  return __uint_as_float(b);
}
__device__ __forceinline__ unsigned short f2h_bits(float f) {
  _Float16 h = (_Float16)f; unsigned short u; __builtin_memcpy(&u, &h, 2); return u;
}
__device__ __forceinline__ float h_bits2f(unsigned short u) {
  _Float16 h; __builtin_memcpy(&h, &u, 2); return (float)h;
}

// ---------------------------------------------------------------------------
// P1 (R15: p0+scan+p1 fused): per-block LDS hist over 4096 edges -> ONE global
// atomicAdd per touched bucket reserves the block's dense range (153K atomics
// total, vs R9's 1.6M wall) -> LDS-ranked scatter to cu. Bucket-internal order
// becomes nondeterministic; per-edge h and the max-reduce are order-exact, so
// output is unchanged. node_pre fused as extra blocks (as p0 was).
// ---------------------------------------------------------------------------
__global__ __launch_bounds__(256) void p1_kernel(
    const int* __restrict__ ei, const float* __restrict__ ea,
    const float* __restrict__ x, const float* __restrict__ W1,
    const float* __restrict__ b1,
    float* __restrict__ P, _Float16* __restrict__ Q,
    unsigned* __restrict__ bktAlloc,
    uint2* __restrict__ cu, unsigned char* __restrict__ cdlo,
    uint4* __restrict__ ovf, int* __restrict__ ovf_cnt,
    int E, int N, int nSB, int NBKT)
{
  if (blockIdx.x < (unsigned)nSB) {
    __shared__ unsigned hcnt[512];              // NBKT <= 512 (N <= 65536)
    __shared__ unsigned hbase[512];
    for (int i = threadIdx.x; i < NBKT; i += 256) hcnt[i] = 0;
    __syncthreads();
    const int base = blockIdx.x * EPB;
    // ---- pass 1: block-local histogram (LDS atomics) ----
#pragma unroll 1
    for (int r = 0; r < 4; ++r) {
      const int b2 = base + r * 1024;
      int dd[4]; bool vv[4];
#pragma unroll
      for (int i = 0; i < 4; ++i) {
        int e = b2 + i * 256 + threadIdx.x;
        vv[i] = e < E;
        dd[i] = ei[(size_t)E + (vv[i] ? e : 0)];
      }
#pragma unroll
      for (int i = 0; i < 4; ++i)
        if (vv[i]) atomicAdd(&hcnt[dd[i] >> 7], 1u);
    }
    __syncthreads();
    // ---- reserve dense ranges: one global atomic per touched bucket ----
    for (int i = threadIdx.x; i < NBKT; i += 256) {
      const unsigned c = hcnt[i];
      hbase[i] = c ? atomicAdd(&bktAlloc[i], c) : 0u;
      hcnt[i] = 0;                               // reuse as running rank
    }
    __syncthreads();
    // ---- pass 2: scatter with pos = hbase[b] + rank ----
#pragma unroll 1
    for (int r = 0; r < 4; ++r) {
      const int b2 = base + r * 1024;
      int s[4], d[4]; bool v[4];
#pragma unroll
      for (int i = 0; i < 4; ++i) {
        int e = b2 + i * 256 + threadIdx.x;
        v[i] = e < E;
        int ec = v[i] ? e : 0;
        s[i] = ei[ec];
        d[i] = ei[(size_t)E + ec];
      }
      float a0[4], a1[4], a2[4];
#pragma unroll
      for (int i = 0; i < 4; ++i) {
        int ec = v[i] ? (b2 + i * 256 + threadIdx.x) : 0;
        a0[i] = ea[ec * 3 + 0]; a1[i] = ea[ec * 3 + 1]; a2[i] = ea[ec * 3 + 2];
      }
#pragma unroll
      for (int i = 0; i < 4; ++i) {
        if (!v[i]) continue;
        const int b = d[i] >> 7;
        const unsigned rr = atomicAdd(&hcnt[b], 1u);               // LDS rank
        const unsigned pos = hbase[b] + rr;
        uint2 pay;
        pay.x = (unsigned)s[i] | ((unsigned)f2h_bits(a0[i]) << 16);  // src < 65536
        pay.y = (unsigned)f2h_bits(a1[i]) | ((unsigned)f2h_bits(a2[i]) << 16);
        if (pos < CAPB) {
          cu[(size_t)b * CAPB + pos] = pay;
          cdlo[(size_t)b * CAPB + pos] = (unsigned char)(d[i] & (DPB - 1));
        } else {
          int oi = atomicAdd(ovf_cnt, 1);
          if (oi < OVF_CAP) ovf[oi] = make_uint4(pay.x, pay.y, (unsigned)d[i], 0u);
        }
      }
    }
    return;
  }
  // ---------------- node_pre ----------------
  const int lane = threadIdx.x & 63;
  float w1d[IN_F], w1b[IN_F];
#pragma unroll
  for (int c = 0; c < IN_F; ++c) {
    w1b[c] = W1[(IN_F + c) * HID + lane];
    w1d[c] = W1[c * HID + lane] - w1b[c];
  }
  const float b1v = b1[lane];
  int gw = __builtin_amdgcn_readfirstlane((((int)blockIdx.x - nSB) << 2) | (threadIdx.x >> 6));
  const int nwaves = 512 << 2;
  for (int n = gw; n < N; n += nwaves) {
    float p = b1v, q = 0.f;
#pragma unroll
    for (int c = 0; c < IN_F; ++c) {
      float xv = x[n * IN_F + c];
      p = fmaf(xv, w1d[c], p);
      q = fmaf(xv, w1b[c], q);
    }
    P[n * HID + lane] = p;
    Q[n * HID + lane] = (_Float16)q;
  }
}

// ---------------------------------------------------------------------------
// P2: per-bucket final scatter. LDS per-dst rank (128 counters) -> linear
// rec[d*RSL + rank]; writes cnt[d]. Totals read from bktAlloc.
// ---------------------------------------------------------------------------
__global__ __launch_bounds__(512) void p2_kernel(
    const uint2* __restrict__ cu, const unsigned char* __restrict__ cdlo,
    const unsigned* __restrict__ bktAlloc,
    uint2* __restrict__ rec, int* __restrict__ cnt,
    uint4* __restrict__ ovf, int* __restrict__ ovf_cnt, int N)
{
  __shared__ int c[DPB];
  const int b = blockIdx.x;
  const int tid = threadIdx.x;
  if (tid < DPB) c[tid] = 0;
  __syncthreads();
  const int nE = (int)min(bktAlloc[b], (unsigned)CAPB);
  for (int i = tid; i < nE; i += 512) {
    const uint2 pay = cu[(size_t)b * CAPB + i];
    const int dlo = cdlo[(size_t)b * CAPB + i];
    const int r = atomicAdd(&c[dlo], 1);                          // LDS atomic
    const int d = b * DPB + dlo;
    if (r < RSL) rec[(size_t)d * RSL + r] = pay;
    else {
      int oi = atomicAdd(ovf_cnt, 1);
      if (oi < OVF_CAP) ovf[oi] = make_uint4(pay.x, pay.y, (unsigned)d, 0u);
    }
  }
  __syncthreads();
  if (tid < DPB) {
    const int d = b * DPB + tid;
    if (d < N) cnt[d] = c[tid];
  }
}

// ---------------------------------------------------------------------------
// bucket: R11/R14 version VERBATIM (measured 105-115 us band; dur x VALUBusy
// ~= 72 us-equiv invariant). Octet-pipelined Q double-buffer, strided dst
// assignment, padded records, VGPR ~60. Straight-line loads (R13 lesson:
// guarded loads double stall at identical VALU work).
// ---------------------------------------------------------------------------
__global__ __launch_bounds__(256) void bucket_kernel(
    const uint2* __restrict__ rec, const int* __restrict__ cnt,
    const float* __restrict__ W1, const float* __restrict__ W2,
    const float* __restrict__ P, const _Float16* __restrict__ Q,
    unsigned* __restrict__ agg, int N)
{
  __shared__ __align__(16) _Float16 hB[4][16][72];     // [wave][edge][ch]

  const int wave = threadIdx.x >> 6;
  const int lane = threadIdx.x & 63;
  const int quad = lane >> 4;
  const int eidx = lane & 15;
  // channel this lane stores in the final permuted row write
  const int mych = ((eidx >> 2) << 4) + (quad << 2) + (eidx & 3);

  // A-operand: W2^T fragments, fp16, loop-invariant (R2-verified).
  v8h a_frag[4][2];
#pragma unroll
  for (int t = 0; t < 4; ++t)
#pragma unroll
    for (int ks = 0; ks < 2; ++ks)
#pragma unroll
      for (int j = 0; j < 8; ++j)
        a_frag[t][ks][j] = (_Float16)W2[(ks * 32 + quad * 8 + j) * HID + t * 16 + eidx];

  const float w1c0 = W1[(2 * IN_F + 0) * HID + lane];
  const float w1c1 = W1[(2 * IN_F + 1) * HID + lane];
  const float w1c2 = W1[(2 * IN_F + 2) * HID + lane];

  const int gwave = __builtin_amdgcn_readfirstlane((blockIdx.x << 2) | wave);
  const int nw = gridDim.x << 2;

  int d = gwave;
  if (d >= N) return;   // waves are independent (no cross-wave LDS / syncthreads)

  int m; uint2 r0, r1; float pP;
  auto prefetch = [&](int dd) {
    m = min(cnt[dd], RSL);
    if (lane < m) r0 = rec[(size_t)dd * RSL + lane];
    if (m > 64) {       // wave-uniform rare branch (records 64..m)
      if (64 + lane < m) r1 = rec[(size_t)dd * RSL + 64 + lane];
    }
    pP = P[(size_t)dd * HID + lane];
  };

  prefetch(d);

  while (d < N) {
    const int dn = d + nw;
    const int m_cur = m;
    const float pvl = pP;
    uint2 ra = r0, rb = r1;   // active records for this dst

    if (m_cur > 0) {
      // ---- pad reg records: lanes >= m_cur get a copy of the last record ----
      {
        const int lm = m_cur - 1;
        unsigned rlx, rly;
        if (lm < 64) {
          rlx = (unsigned)__builtin_amdgcn_readlane((int)ra.x, lm);
          rly = (unsigned)__builtin_amdgcn_readlane((int)ra.y, lm);
        } else {
          rlx = (unsigned)__builtin_amdgcn_readlane((int)rb.x, lm & 63);
          rly = (unsigned)__builtin_amdgcn_readlane((int)rb.y, lm & 63);
        }
        if (lane >= m_cur)      { ra.x = rlx; ra.y = rly; }
        if (lane + 64 >= m_cur) { rb.x = rlx; rb.y = rly; }
      }

      // ---- preload octets 0,1 (uniform src -> saddr loads) ----
      float qvA[8], qvB[8];
#pragma unroll
      for (int i = 0; i < 8; ++i) {
        unsigned sx = (unsigned)__builtin_amdgcn_readlane((int)ra.x, i) & 0xFFFFu;
        qvA[i] = (float)Q[(size_t)sx * HID + lane];
      }
#pragma unroll
      for (int i = 0; i < 8; ++i) {
        unsigned sx = (unsigned)__builtin_amdgcn_readlane((int)ra.x, 8 + i) & 0xFFFFu;
        qvB[i] = (float)Q[(size_t)sx * HID + lane];
      }

      // ---- prefetch next dst (cnt -> records -> P), lands under tile work ----
      if (dn < N) prefetch(dn);

      // ---- process current dst: 16-edge MFMA tiles (ntile <= 5) ----
      float maxv[4][4];
#pragma unroll
      for (int t = 0; t < 4; ++t)
#pragma unroll
        for (int r = 0; r < 4; ++r) maxv[t][r] = -INFINITY;

      const int ntile = (m_cur + 15) >> 4;
      const int noct = ntile << 1;
      for (int tb = 0; tb < ntile; ++tb) {
        const unsigned rsx = (tb < 4) ? ra.x : rb.x;
        const unsigned rsy = (tb < 4) ? ra.y : rb.y;
        const int b16 = (tb & 3) << 4;

        // build rows 0-7 from qvA (octet 2tb)
#pragma unroll
        for (int i = 0; i < 8; ++i) {
          const unsigned rx = (unsigned)__builtin_amdgcn_readlane((int)rsx, b16 + i);
          const unsigned ry = (unsigned)__builtin_amdgcn_readlane((int)rsy, b16 + i);
          float pre = pvl + qvA[i];
          pre = fmaf(h_bits2f((unsigned short)(rx >> 16)), w1c0, pre);
          pre = fmaf(h_bits2f((unsigned short)(ry & 0xFFFFu)), w1c1, pre);
          pre = fmaf(h_bits2f((unsigned short)(ry >> 16)), w1c2, pre);
          hB[wave][i][lane] = (_Float16)fmaxf(pre, 0.f);
        }
        // reissue qvA <- octet 2tb+2 (covered by rows 8-15 build + MFMA + next rows 0-7)
        {
          const int o = 2 * tb + 2;
          if (o < noct) {
            const unsigned rox = (o < 8) ? ra.x : rb.x;
            const int bo = (o & 7) << 3;
#pragma unroll
            for (int i = 0; i < 8; ++i) {
              unsigned sx = (unsigned)__builtin_amdgcn_readlane((int)rox, bo + i) & 0xFFFFu;
              qvA[i] = (float)Q[(size_t)sx * HID + lane];
            }
          }
        }
        // build rows 8-15 from qvB (octet 2tb+1)
#pragma unroll
        for (int i = 0; i < 8; ++i) {
          const unsigned rx = (unsigned)__builtin_amdgcn_readlane((int)rsx, b16 + 8 + i);
          const unsigned ry = (unsigned)__builtin_amdgcn_readlane((int)rsy, b16 + 8 + i);
          float pre = pvl + qvB[i];
          pre = fmaf(h_bits2f((unsigned short)(rx >> 16)), w1c0, pre);
          pre = fmaf(h_bits2f((unsigned short)(ry & 0xFFFFu)), w1c1, pre);
          pre = fmaf(h_bits2f((unsigned short)(ry >> 16)), w1c2, pre);
          hB[wave][8 + i][lane] = (_Float16)fmaxf(pre, 0.f);
        }
        // reissue qvB <- octet 2tb+3
        {
          const int o = 2 * tb + 3;
          if (o < noct) {
            const unsigned rox = (o < 8) ? ra.x : rb.x;
            const int bo = (o & 7) << 3;
#pragma unroll
            for (int i = 0; i < 8; ++i) {
              unsigned sx = (unsigned)__builtin_amdgcn_readlane((int)rox, bo + i) & 0xFFFFu;
              qvB[i] = (float)Q[(size_t)sx * HID + lane];
            }
          }
        }
        __builtin_amdgcn_wave_barrier();

        const v8h bf0 = *(const v8h*)&hB[wave][eidx][quad * 8];
        const v8h bf1 = *(const v8h*)&hB[wave][eidx][32 + quad * 8];
#pragma unroll
        for (int t = 0; t < 4; ++t) {
          v4f acc = (v4f){0.f, 0.f, 0.f, 0.f};
          acc = __builtin_amdgcn_mfma_f32_16x16x32_f16(a_frag[t][0], bf0, acc, 0, 0, 0);
          acc = __builtin_amdgcn_mfma_f32_16x16x32_f16(a_frag[t][1], bf1, acc, 0, 0, 0);
#pragma unroll
          for (int r = 0; r < 4; ++r) maxv[t][r] = fmaxf(maxv[t][r], acc[r]);
        }
        __builtin_amdgcn_wave_barrier();
      }

      // ---- butterfly max over the 16 edge-columns, direct permuted row store ----
#pragma unroll
      for (int t = 0; t < 4; ++t)
#pragma unroll
        for (int r = 0; r < 4; ++r) {
          float v = maxv[t][r];
          v = fmaxf(v, __shfl_xor(v, 1, 64));
          v = fmaxf(v, __shfl_xor(v, 2, 64));
          v = fmaxf(v, __shfl_xor(v, 4, 64));
          v = fmaxf(v, __shfl_xor(v, 8, 64));
          maxv[t][r] = v;
        }
      float val = maxv[0][0];
#pragma unroll
      for (int t = 0; t < 4; ++t)
#pragma unroll
        for (int r = 0; r < 4; ++r)
          val = (eidx == t * 4 + r) ? maxv[t][r] : val;
      agg[(size_t)d * HID + mych] = ordenc(val);   // permutation within one 256B row
    } else {
      // empty dst; still run the next-dst prefetch to keep the pipeline primed
      if (dn < N) prefetch(dn);
      agg[(size_t)d * HID + lane] = ORD_NEG_INF;
    }
    d = dn;
  }
}

// Fallback for overflow (expected ~0). Payload-form records {src|a0, a1|a2, d}.
// Same fp16-attr math as bucket, fp32 accumulation; atomicMax after bucket.
__global__ __launch_bounds__(256) void overflow_kernel(
    const uint4* __restrict__ ovf, const int* __restrict__ ovf_cnt,
    const float* __restrict__ W1, const float* __restrict__ W2,
    const float* __restrict__ P, const _Float16* __restrict__ Q,
    unsigned* __restrict__ agg)
{
  __shared__ float hsh[4][HID];
  const int wave = threadIdx.x >> 6;
  const int lane = threadIdx.x & 63;

  int M = *ovf_cnt;
  if (M > OVF_CAP) M = OVF_CAP;
  if (M == 0) return;

  float w2r[HID];
#pragma unroll
  for (int j = 0; j < HID; ++j) w2r[j] = W2[j * HID + lane];
  const float w1c0 = W1[(2 * IN_F + 0) * HID + lane];
  const float w1c1 = W1[(2 * IN_F + 1) * HID + lane];
  const float w1c2 = W1[(2 * IN_F + 2) * HID + lane];

  const int gwave = __builtin_amdgcn_readfirstlane((blockIdx.x << 2) | wave);
  const int nw = gridDim.x << 2;
  for (int k = gwave; k < M; k += nw) {
    const uint4 o = ovf[k];
    const int s = (int)(o.x & 0xFFFFu);
    const int d = (int)o.z;
    float pre = P[(size_t)d * HID + lane] + (float)Q[(size_t)s * HID + lane];
    pre = fmaf(h_bits2f((unsigned short)(o.x >> 16)), w1c0, pre);
    pre = fmaf(h_bits2f((unsigned short)(o.y & 0xFFFFu)), w1c1, pre);
    pre = fmaf(h_bits2f((unsigned short)(o.y >> 16)), w1c2, pre);
    hsh[wave][lane] = fmaxf(pre, 0.f);
    __builtin_amdgcn_wave_barrier();
    float mv = 0.f;
#pragma unroll
    for (int j = 0; j < HID; ++j) mv = fmaf(hsh[wave][j], w2r[j], mv);
    atomicMax(&agg[(size_t)d * HID + lane], ordenc(mv));
    __builtin_amdgcn_wave_barrier();
  }
}

// 16 nodes per block: decode agg (empty -> 0, else +b2), out = sigmoid(agg @ Wo + bo)
__global__ __launch_bounds__(256) void out_kernel(
    const unsigned* __restrict__ agg,
    const float* __restrict__ b2,
    const float* __restrict__ Wo, const float* __restrict__ bo,
    float* __restrict__ out, int N)
{
  __shared__ float Wos[HID * OUTF];
  __shared__ float bos[OUTF];
  __shared__ float b2s[HID];
  __shared__ float aggs[16][HID + 1];

  for (int i = threadIdx.x; i < HID * OUTF; i += 256) Wos[i] = Wo[i];
  if (threadIdx.x < OUTF) bos[threadIdx.x] = bo[threadIdx.x];
  if (threadIdx.x < HID) b2s[threadIdx.x] = b2[threadIdx.x];
  __syncthreads();

  const int nodeBase = blockIdx.x * 16;
  {
    int ln = threadIdx.x >> 4;
    int k0 = (threadIdx.x & 15) * 4;
    int n = nodeBase + ln;
    if (n < N) {
      const uint4 u = *(const uint4*)&agg[(size_t)n * HID + k0];
      aggs[ln][k0 + 0] = (u.x == ORD_NEG_INF) ? 0.f : orddec(u.x) + b2s[k0 + 0];
      aggs[ln][k0 + 1] = (u.y == ORD_NEG_INF) ? 0.f : orddec(u.y) + b2s[k0 + 1];
      aggs[ln][k0 + 2] = (u.z == ORD_NEG_INF) ? 0.f : orddec(u.z) + b2s[k0 + 2];
      aggs[ln][k0 + 3] = (u.w == ORD_NEG_INF) ? 0.f : orddec(u.w) + b2s[k0 + 3];
    }
  }
  __syncthreads();
  {
    int ln = threadIdx.x >> 4;
    int o = threadIdx.x & 15;
    int n = nodeBase + ln;
    if (n < N) {
      float acc = bos[o];
#pragma unroll
      for (int k = 0; k < HID; ++k) acc = fmaf(aggs[ln][k], Wos[k * OUTF + o], acc);
      out[n * OUTF + o] = 1.f / (1.f + __expf(-acc));
    }
  }
}

extern "C" void kernel_launch(void* const* d_in, const int* in_sizes, int n_in,
                              void* d_out, int out_size, void* d_ws, size_t ws_size,
                              hipStream_t stream) {
  const float* x  = (const float*)d_in[0];
  const int*   ei = (const int*)d_in[1];
  const float* ea = (const float*)d_in[2];
  const float* W1 = (const float*)d_in[3];
  const float* b1 = (const float*)d_in[4];
  const float* W2 = (const float*)d_in[5];
  const float* b2 = (const float*)d_in[6];
  const float* Wo = (const float*)d_in[7];
  const float* bo = (const float*)d_in[8];
  float* out = (float*)d_out;

  const int N = in_sizes[0] / IN_F;    // 50000
  const int E = in_sizes[1] / 2;       // 1600000
  const int NBKT = (N + DPB - 1) / DPB;   // 391
  const int nSB  = (E + EPB - 1) / EPB;   // 391 (4096 edges/block)

  // ws layout (16B-aligned regions), ~84 MB total:
  // P(12.8M) | Q fp16(6.4M) | agg(12.8M) | rec N*RSL*8(32M) | cu NBKT*CAPB*8(16M)
  // | cnt(0.2M) | cdlo NBKT*CAPB(2M) | bktAlloc(NBKT*4) | ovf_cnt | ovf(1M)
  char* w = (char*)d_ws;
  auto align16 = [](size_t v) { return (v + 15) & ~(size_t)15; };
  float*     Pp   = (float*)w;       w += align16((size_t)N * HID * 4);
  _Float16*  Qp   = (_Float16*)w;    w += align16((size_t)N * HID * 2);
  unsigned*  agg  = (unsigned*)w;    w += align16((size_t)N * HID * 4);
  uint2*     rec  = (uint2*)w;       w += align16((size_t)N * RSL * 8);
  uint2*     cu   = (uint2*)w;       w += align16((size_t)NBKT * CAPB * 8);
  int*       cnt  = (int*)w;         w += align16((size_t)N * 4);
  unsigned char* cdlo = (unsigned char*)w; w += align16((size_t)NBKT * CAPB);
  unsigned* bktAlloc = (unsigned*)w; w += align16((size_t)NBKT * 4);
  int*   ovf_cnt  = (int*)w;         w += 16;
  uint4*     ovf  = (uint4*)w;

  // zero bktAlloc + ovf_cnt in one memset (they are adjacent)
  hipMemsetAsync(bktAlloc, 0, align16((size_t)NBKT * 4) + 16, stream);

  p1_kernel<<<nSB + 512, 256, 0, stream>>>(
      ei, ea, x, W1, b1, Pp, Qp, bktAlloc, cu, cdlo, ovf, ovf_cnt, E, N, nSB, NBKT);
  p2_kernel<<<NBKT, 512, 0, stream>>>(cu, cdlo, bktAlloc, rec, cnt, ovf, ovf_cnt, N);
  bucket_kernel<<<4096, 256, 0, stream>>>(rec, cnt, W1, W2, Pp, Qp, agg, N);
  overflow_kernel<<<256, 256, 0, stream>>>(ovf, ovf_cnt, W1, W2, Pp, Qp, agg);
  out_kernel<<<(N + 15) / 16, 256, 0, stream>>>(agg, b2, Wo, bo, out, N);
}